// Round 7
// baseline (247.344 us; speedup 1.0000x reference)
//
#include <hip/hip_runtime.h>
#include <hip/hip_bf16.h>
#include <hip/hip_cooperative_groups.h>

namespace cg = cooperative_groups;

#define D_FEAT 64
#define OVF_CAP 65536
#define NBIN 256             // blocks that do edge binning in phase 1
#define NBMAX 1024           // max buckets (128 nodes each -> n <= 131072)
#define CSLOT 32             // slot capacity per node

typedef unsigned int uint32;

__device__ inline float blo(uint32 u) { return __uint_as_float(u << 16); }
__device__ inline float bhi(uint32 u) { return __uint_as_float(u & 0xffff0000u); }
__device__ inline float dinv(int d) { return (d > 0) ? rsqrtf((float)d) : 0.0f; }

// ================= single cooperative kernel: bin -> rank -> gather =========
// Phase 1: 256 blocks bin edges into CAP-padded 128-node bucket segments
//          (LDS hist + one global-atomic reservation per (block,bucket));
//          all blocks share the bf16 cast of x.   grid.sync()
// Phase 2: block k ranks its bucket's edges into LDS slot lists (slots never
//          touch global memory) and writes deg/winv.   grid.sync()
// Phase 3: 8 waves x 16 nodes/wave gather from LDS slots (verified 4-edge-
//          parallel body; xb random-128B fetch profile unchanged).
__global__ __launch_bounds__(512, 8) void k_coop(
    const int* __restrict__ row, const int* __restrict__ col,
    const float2* __restrict__ x2, uint32* __restrict__ xb,
    int* __restrict__ deg, float* __restrict__ winv,
    int* __restrict__ cursor, uint32* __restrict__ binned,
    int2* __restrict__ ovf, int* __restrict__ ovf_cnt,
    const float* __restrict__ alpha_p, const float* __restrict__ rs_p,
    const float4* __restrict__ x4, float4* __restrict__ out4,
    int n, int E, int nb, int CAP, int EB2, int nhalf)
{
    __shared__ int   slots[128 * CSLOT];   // 16 KB; aliased as hist in phase 1
    __shared__ int   cnt[128];
    __shared__ float winvl[128];
    const int bid = blockIdx.x;
    const int tid = threadIdx.x;
    cg::grid_group grid = cg::this_grid();

    // ---------------- phase 1: bin + cast ----------------
    if (bid < NBIN) {
        int* h = slots;                    // nb <= 1024 ints fit in slots
        for (int i = tid; i < nb; i += 512) h[i] = 0;
        __syncthreads();
        const int s = bid * EB2;
        const int e = (s + EB2 < E) ? s + EB2 : E;
        for (int i = s + tid; i < e; i += 512)
            atomicAdd(&h[col[i] >> 7], 1);
        __syncthreads();
        for (int k = tid; k < nb; k += 512) {
            int c = h[k];
            if (c) h[k] = atomicAdd(&cursor[k], c);   // h[k] := segment base
        }
        __syncthreads();
        for (int i = s + tid; i < e; i += 512) {
            int c = col[i];
            uint32 r = (uint32)row[i];
            int b = c >> 7;
            int pos = atomicAdd(&h[b], 1);            // LDS cursor
            if (pos < CAP) {
                binned[(size_t)b * CAP + pos] = (r << 7) | (uint32)(c & 127);
            } else {
                atomicAdd(&deg[c], 1);                // preseed exact degree
                int o = atomicAdd(ovf_cnt, 1);
                if (o < OVF_CAP) ovf[o] = make_int2((int)r, c);
            }
        }
    }
    // fused bf16 cast (all blocks)
    for (int j = bid * 512 + tid; j < nhalf; j += nb * 512) {
        float2 v = x2[j];
        __hip_bfloat16 bx = __float2bfloat16(v.x);
        __hip_bfloat16 by = __float2bfloat16(v.y);
        uint32 ux = *reinterpret_cast<unsigned short*>(&bx);
        uint32 uy = *reinterpret_cast<unsigned short*>(&by);
        xb[j] = ux | (uy << 16);
    }
    grid.sync();

    // ---------------- phase 2: rank into LDS slots + deg/winv ----------------
    if (tid < 128) cnt[tid] = 0;
    __syncthreads();
    const int base = bid << 7;
    int tot = cursor[bid];
    if (tot > CAP) tot = CAP;
    const uint32* seg = binned + (size_t)bid * CAP;
    for (int i = tid; i < tot; i += 512) {
        uint32 pk = seg[i];
        int cl = (int)(pk & 127);
        int r  = (int)(pk >> 7);
        int rk = atomicAdd(&cnt[cl], 1);              // LDS atomic
        if (rk < CSLOT) {
            slots[(cl << 5) + rk] = r;
        } else {
            int o = atomicAdd(ovf_cnt, 1);
            if (o < OVF_CAP) ovf[o] = make_int2(r, base + cl);
        }
    }
    __syncthreads();
    if (tid < 128) {
        int node = base + tid;
        if (node < n) {
            int d = cnt[tid] + deg[node];             // + CAP-overflow preseed
            deg[node] = d;
            float w = dinv(d);
            winv[node] = w;
            winvl[tid] = w;
        } else {
            winvl[tid] = 0.f;
        }
    }
    grid.sync();

    // ---------------- phase 3: gather (4 edges parallel, 16-edge unroll) ----
    const int wv   = tid >> 6;                        // wave 0..7
    const int lane = tid & 63;
    const int q = lane >> 4;                          // edge group 0..3
    const int l = lane & 15;                          // float4 index in row
    const float alpha = *alpha_p;
    const float rs = *rs_p;
    for (int nl = (wv << 4); nl < (wv << 4) + 16; ++nl) {   // 16 nodes/wave
        int node = base + nl;
        if (node >= n) break;                         // wave-uniform
        int e = cnt[nl];
        if (e > CSLOT) e = CSLOT;
        float4 xr = make_float4(0.f, 0.f, 0.f, 0.f);
        if (q == 0) xr = x4[(size_t)node * 16 + l];   // hoisted residual load
        const int* sl = &slots[nl << 5];
        float ax = 0.f, ay = 0.f, az = 0.f, aw = 0.f;
        int k = 0;
        for (; k + 16 <= e; k += 16) {
            int s0 = sl[k + q];
            int s1 = sl[k + 4 + q];
            int s2 = sl[k + 8 + q];
            int s3 = sl[k + 12 + q];
            float w0 = winv[s0], w1 = winv[s1], w2 = winv[s2], w3 = winv[s3];
            uint2 p0 = ((const uint2*)(xb + (size_t)s0 * 32))[l];
            uint2 p1 = ((const uint2*)(xb + (size_t)s1 * 32))[l];
            uint2 p2 = ((const uint2*)(xb + (size_t)s2 * 32))[l];
            uint2 p3 = ((const uint2*)(xb + (size_t)s3 * 32))[l];
            ax = fmaf(w0, blo(p0.x), ax); ay = fmaf(w0, bhi(p0.x), ay);
            az = fmaf(w0, blo(p0.y), az); aw = fmaf(w0, bhi(p0.y), aw);
            ax = fmaf(w1, blo(p1.x), ax); ay = fmaf(w1, bhi(p1.x), ay);
            az = fmaf(w1, blo(p1.y), az); aw = fmaf(w1, bhi(p1.y), aw);
            ax = fmaf(w2, blo(p2.x), ax); ay = fmaf(w2, bhi(p2.x), ay);
            az = fmaf(w2, blo(p2.y), az); aw = fmaf(w2, bhi(p2.y), aw);
            ax = fmaf(w3, blo(p3.x), ax); ay = fmaf(w3, bhi(p3.x), ay);
            az = fmaf(w3, blo(p3.y), az); aw = fmaf(w3, bhi(p3.y), aw);
        }
        for (; k < e; k += 4) {
            int kk = k + q;
            if (kk < e) {
                int s0 = sl[kk];
                float w0 = winv[s0];
                uint2 p0 = ((const uint2*)(xb + (size_t)s0 * 32))[l];
                ax = fmaf(w0, blo(p0.x), ax); ay = fmaf(w0, bhi(p0.x), ay);
                az = fmaf(w0, blo(p0.y), az); aw = fmaf(w0, bhi(p0.y), aw);
            }
        }
        ax += __shfl_down(ax, 32, 64); ay += __shfl_down(ay, 32, 64);
        az += __shfl_down(az, 32, 64); aw += __shfl_down(aw, 32, 64);
        ax += __shfl_down(ax, 16, 64); ay += __shfl_down(ay, 16, 64);
        az += __shfl_down(az, 16, 64); aw += __shfl_down(aw, 16, 64);
        if (q == 0) {
            float adw = alpha * winvl[nl];
            float4 o;
            o.x = fmaf(adw, ax, rs * xr.x);
            o.y = fmaf(adw, ay, rs * xr.y);
            o.z = fmaf(adw, az, rs * xr.z);
            o.w = fmaf(adw, aw, rs * xr.w);
            out4[(size_t)node * 16 + l] = o;
        }
    }
}

// ---- overflow fix-up (deg>CSLOT or CAP overflow; empty for uniform input) ----
__global__ void k_ovf(const int2* __restrict__ ovf, const int* __restrict__ cnt_p,
                      const float* __restrict__ x, const float* __restrict__ winv,
                      const float* __restrict__ alpha_p, float* __restrict__ out) {
    int cnt = *cnt_p;
    if (cnt > OVF_CAP) cnt = OVF_CAP;
    if (cnt <= 0) return;
    float a = *alpha_p;
    long long total = (long long)cnt * 64;
    long long stride = (long long)gridDim.x * blockDim.x;
    for (long long idx = blockIdx.x * (long long)blockDim.x + threadIdx.x;
         idx < total; idx += stride) {
        int e = (int)(idx >> 6);
        int f = (int)(idx & 63);
        int2 rc = ovf[e];
        float w = a * winv[rc.x] * winv[rc.y];
        atomicAdd(&out[(size_t)rc.y * D_FEAT + f], w * x[(size_t)rc.x * D_FEAT + f]);
    }
}

// ---- winv table for the fallback path ----
__global__ void k_winv(const int* __restrict__ deg, float* __restrict__ winv, int n) {
    int i = blockIdx.x * blockDim.x + threadIdx.x;
    if (i < n) winv[i] = dinv(deg[i]);
}

// ================= fallback: direct padded-CSR build (round 4) ===============
__global__ __launch_bounds__(256) void k_prep(const float2* __restrict__ x2,
                                              uint32* __restrict__ xb,
                                              const int* __restrict__ row,
                                              const int* __restrict__ col,
                                              int* __restrict__ deg,
                                              int* __restrict__ slots,
                                              int2* __restrict__ ovf,
                                              int* __restrict__ ovf_cnt,
                                              int nhalf, int E, int C) {
    const int t = blockIdx.x * blockDim.x + threadIdx.x;
    if (t < E) {
        int c = col[t];
        int r = row[t];
        int rk = atomicAdd(&deg[c], 1);
        if (rk < C) {
            slots[(size_t)c * C + rk] = r;
        } else {
            int o = atomicAdd(ovf_cnt, 1);
            if (o < OVF_CAP) ovf[o] = make_int2(r, c);
        }
    }
    const int stride = gridDim.x * blockDim.x;
    for (int j = t; j < nhalf; j += stride) {
        float2 v = x2[j];
        __hip_bfloat16 bx = __float2bfloat16(v.x);
        __hip_bfloat16 by = __float2bfloat16(v.y);
        uint32 ux = *reinterpret_cast<unsigned short*>(&bx);
        uint32 uy = *reinterpret_cast<unsigned short*>(&by);
        xb[j] = ux | (uy << 16);
    }
}

// fallback gather (global slots; verified round-0 body)
__global__ void k_gather4d(const uint32* __restrict__ xb,
                           const float4* __restrict__ x4,
                           const int* __restrict__ deg,
                           const float* __restrict__ winv,
                           const int* __restrict__ slots,
                           const float* __restrict__ alpha_p,
                           const float* __restrict__ rs_p,
                           float4* __restrict__ out4, int n, int C) {
    int wid = (blockIdx.x * blockDim.x + threadIdx.x) >> 6;
    if (wid >= n) return;
    const int lane = threadIdx.x & 63;
    const int q = lane >> 4;
    const int l = lane & 15;
    int d = deg[wid];
    int e = (d < C) ? d : C;
    float4 xr = make_float4(0.f, 0.f, 0.f, 0.f);
    if (q == 0) xr = x4[(size_t)wid * 16 + l];
    const int* sl = slots + (size_t)wid * C;
    float ax = 0.f, ay = 0.f, az = 0.f, aw = 0.f;
    int k = 0;
    for (; k + 16 <= e; k += 16) {
        int s0 = sl[k + q];
        int s1 = sl[k + 4 + q];
        int s2 = sl[k + 8 + q];
        int s3 = sl[k + 12 + q];
        float w0 = winv[s0], w1 = winv[s1], w2 = winv[s2], w3 = winv[s3];
        uint2 p0 = ((const uint2*)(xb + (size_t)s0 * 32))[l];
        uint2 p1 = ((const uint2*)(xb + (size_t)s1 * 32))[l];
        uint2 p2 = ((const uint2*)(xb + (size_t)s2 * 32))[l];
        uint2 p3 = ((const uint2*)(xb + (size_t)s3 * 32))[l];
        ax = fmaf(w0, blo(p0.x), ax); ay = fmaf(w0, bhi(p0.x), ay);
        az = fmaf(w0, blo(p0.y), az); aw = fmaf(w0, bhi(p0.y), aw);
        ax = fmaf(w1, blo(p1.x), ax); ay = fmaf(w1, bhi(p1.x), ay);
        az = fmaf(w1, blo(p1.y), az); aw = fmaf(w1, bhi(p1.y), aw);
        ax = fmaf(w2, blo(p2.x), ax); ay = fmaf(w2, bhi(p2.x), ay);
        az = fmaf(w2, blo(p2.y), az); aw = fmaf(w2, bhi(p2.y), aw);
        ax = fmaf(w3, blo(p3.x), ax); ay = fmaf(w3, bhi(p3.x), ay);
        az = fmaf(w3, blo(p3.y), az); aw = fmaf(w3, bhi(p3.y), aw);
    }
    for (; k < e; k += 4) {
        int kk = k + q;
        if (kk < e) {
            int s0 = sl[kk];
            float w0 = winv[s0];
            uint2 p0 = ((const uint2*)(xb + (size_t)s0 * 32))[l];
            ax = fmaf(w0, blo(p0.x), ax); ay = fmaf(w0, bhi(p0.x), ay);
            az = fmaf(w0, blo(p0.y), az); aw = fmaf(w0, bhi(p0.y), aw);
        }
    }
    ax += __shfl_down(ax, 32, 64); ay += __shfl_down(ay, 32, 64);
    az += __shfl_down(az, 32, 64); aw += __shfl_down(aw, 32, 64);
    ax += __shfl_down(ax, 16, 64); ay += __shfl_down(ay, 16, 64);
    az += __shfl_down(az, 16, 64); aw += __shfl_down(aw, 16, 64);
    if (q == 0) {
        float adw = (*alpha_p) * winv[wid];
        float rs  = *rs_p;
        float4 o;
        o.x = fmaf(adw, ax, rs * xr.x);
        o.y = fmaf(adw, ay, rs * xr.y);
        o.z = fmaf(adw, az, rs * xr.z);
        o.w = fmaf(adw, aw, rs * xr.w);
        out4[(size_t)wid * 16 + l] = o;
    }
}

static inline char* align_up(char* p, size_t a) {
    return (char*)(((uintptr_t)p + (a - 1)) & ~(uintptr_t)(a - 1));
}

extern "C" void kernel_launch(void* const* d_in, const int* in_sizes, int n_in,
                              void* d_out, int out_size, void* d_ws, size_t ws_size,
                              hipStream_t stream) {
    const float* x         = (const float*)d_in[0];
    const float* alpha     = (const float*)d_in[1];
    const float* res_scale = (const float*)d_in[2];
    const int*   ei        = (const int*)d_in[3];

    const int n = in_sizes[0] / D_FEAT;      // 100000
    const int E = in_sizes[3] / 2;           // 1600000
    const int* row = ei;                     // sources
    const int* col = ei + E;                 // targets

    float* out = (float*)d_out;
    const int nhalf = n * (D_FEAT / 2);
    const int nb = (n + 127) >> 7;           // 128-node buckets (782)
    const int EB2 = (E + NBIN - 1) / NBIN;   // edges per binning block

    // ---------- cooperative one-kernel pipeline ----------
    {
        char* p = (char*)d_ws;
        int*    deg     = (int*)p;            p += (size_t)n * 4;
        int*    cursor  = (int*)p;            p += (size_t)nb * 4;
        int*    ovf_cnt = (int*)p;            p += 4;
        float*  winv    = (float*)p;          p += (size_t)n * 4;
        int2*   ovf     = (int2*)p;           p += (size_t)OVF_CAP * 8;
        p = align_up(p, 16);
        uint32* xb      = (uint32*)p;         p += (size_t)n * 128;
        p = align_up(p, 16);
        uint32* binned  = (uint32*)p;
        const size_t fixed = (size_t)((char*)binned - (char*)d_ws);

        int CAP = 0;
        if (ws_size > fixed) {
            long long avail = (long long)(ws_size - fixed) / ((long long)nb * 4);
            CAP = (avail > 4096) ? 4096 : (int)avail;
            CAP &= ~31;
        }

        // co-residency check for cooperative launch (cached)
        static int coop_cap = -1;
        if (coop_cap < 0) {
            int perCU = 0, nCU = 0, dev = 0;
            hipGetDevice(&dev);
            if (hipOccupancyMaxActiveBlocksPerMultiprocessor(&perCU, k_coop,
                                                             512, 0) != hipSuccess)
                perCU = 0;
            if (hipDeviceGetAttribute(&nCU, hipDeviceAttributeMultiprocessorCount,
                                      dev) != hipSuccess)
                nCU = 0;
            coop_cap = perCU * nCU;
        }

        const bool ok = (CAP >= 2560) && (nb <= NBMAX) && (nb <= coop_cap);
        if (ok) {
            hipMemsetAsync(deg, 0, (size_t)(n + nb + 1) * 4, stream);
            const int*    row_a = row;      const int*   col_a = col;
            const float2* x2_a  = (const float2*)x;
            uint32*       xb_a  = xb;       int*         deg_a = deg;
            float*        wv_a  = winv;     int*         cur_a = cursor;
            uint32*       bin_a = binned;   int2*        ovf_a = ovf;
            int*          ovc_a = ovf_cnt;
            const float*  al_a  = alpha;    const float* rs_a  = res_scale;
            const float4* x4_a  = (const float4*)x;
            float4*       out_a = (float4*)out;
            int n_a = n, E_a = E, nb_a = nb, CAP_a = CAP, EB2_a = EB2,
                nh_a = nhalf;
            void* args[] = { &row_a, &col_a, &x2_a, &xb_a, &deg_a, &wv_a,
                             &cur_a, &bin_a, &ovf_a, &ovc_a, &al_a, &rs_a,
                             &x4_a, &out_a, &n_a, &E_a, &nb_a, &CAP_a,
                             &EB2_a, &nh_a };
            hipError_t err = hipLaunchCooperativeKernel(
                (const void*)k_coop, dim3(nb), dim3(512), args, 0, stream);
            if (err == hipSuccess) {
                k_ovf<<<64, 256, 0, stream>>>(ovf, ovf_cnt, x, winv, alpha, out);
                return;
            }
            // else fall through to the non-cooperative fallback
        }
    }

    // ---------- fallback: direct scatter build (round-4 path) ----------
    {
        char* q = (char*)d_ws;
        int*    degf    = (int*)q;            q += (size_t)n * 4;
        int*    ovf_cf  = (int*)q;            q += 4;
        float*  winvf   = (float*)q;          q += (size_t)n * 4;
        int2*   ovff    = (int2*)q;           q += (size_t)OVF_CAP * 8;
        q = align_up(q, 16);
        uint32* xbf     = (uint32*)q;         q += (size_t)n * 128;
        int*    slotsf  = (int*)q;
        const size_t fxd = (size_t)(q - (char*)d_ws);
        int Cf = 0;
        if (ws_size > fxd) {
            size_t c_avail = (ws_size - fxd) / ((size_t)n * 4);
            Cf = (c_avail > 32) ? 32 : (int)c_avail;
        }
        if (Cf < 1) return;
        hipMemsetAsync(degf, 0, (size_t)n * 4 + 4, stream);
        k_prep<<<(E + 255) / 256, 256, 0, stream>>>(
            (const float2*)x, xbf, row, col, degf, slotsf, ovff, ovf_cf,
            nhalf, E, Cf);
        k_winv<<<(n + 255) / 256, 256, 0, stream>>>(degf, winvf, n);
        const long long tt = (long long)n * D_FEAT;
        const int blocks = (int)((tt + 255) / 256);
        k_gather4d<<<blocks, 256, 0, stream>>>(xbf, (const float4*)x, degf, winvf,
                                               slotsf, alpha, res_scale,
                                               (float4*)out, n, Cf);
        k_ovf<<<64, 256, 0, stream>>>(ovff, ovf_cf, x, winvf, alpha, out);
    }
}